// Round 11
// baseline (137.333 us; speedup 1.0000x reference)
//
#include <hip/hip_runtime.h>
#include <hip/hip_bf16.h>

#define NB 8
#define NC 512
#define NO 64
#define NH 64
#define NW 64
#define NHW 4096

typedef __attribute__((ext_vector_type(8))) short bf16x8;
typedef __attribute__((ext_vector_type(4))) float f32x4;

__device__ __forceinline__ void gload16(const void* g, void* l) {
    __builtin_amdgcn_global_load_lds(
        (const __attribute__((address_space(1))) void*)g,
        (__attribute__((address_space(3))) void*)l, 16, 0, 0);
}

__device__ __forceinline__ short f2bf_bits(float f) {
    __hip_bfloat16 h = __float2bfloat16(f);
    short s; __builtin_memcpy(&s, &h, 2); return s;
}
__device__ __forceinline__ float bfbits_to_f(short s) {
    unsigned int u = ((unsigned int)(unsigned short)s) << 16;
    float f; __builtin_memcpy(&f, &u, 4); return f;
}

// K0a: pack Wq|Wk|Wv -> Wbf[640][512] bf16, biases -> bias_all[640] f32
__global__ __launch_bounds__(256) void pack_w(
    const float* __restrict__ Wq, const float* __restrict__ bq,
    const float* __restrict__ Wk, const float* __restrict__ bk,
    const float* __restrict__ Wv, const float* __restrict__ bv,
    __hip_bfloat16* __restrict__ Wbf, float* __restrict__ bias_all)
{
    const int row = blockIdx.x;
    const int t = threadIdx.x;
    const float* src; float bias;
    if (row < 64)       { src = Wq + row*NC;        bias = bq[row]; }
    else if (row < 128) { src = Wk + (row-64)*NC;   bias = bk[row-64]; }
    else                { src = Wv + (row-128)*NC;  bias = bv[row-128]; }
    for (int i = t; i < NC; i += 256)
        Wbf[(size_t)row*NC + i] = __float2bfloat16(src[i]);
    if (t == 0) bias_all[row] = bias;
}

// K1: fused QKV projection, x f32 read direct, NO global_load_lds.
// A (W) fragments: direct global->register loads (L2-hot, 640 KB matrix),
//   canonical octets: af = Wbf[row][ks*64 + gl*8 .. +8].
// B (x): reg-staged depth-2 ping-pong (xrA/xrB), f32->bf16 in reg,
//   ds_write_b128 into swizzled slot oct^(row&7)^((row>>3)&7)  (round-10
//   verified involution, conflict-free on write and read).
// Barrier per K-step drains only lgkmcnt; global loads float across (T14).
__global__ __launch_bounds__(256) void qkv_fused(
    const float* __restrict__ x, const __hip_bfloat16* __restrict__ Wbf,
    const float* __restrict__ bias_all,
    __hip_bfloat16* __restrict__ qkT2, __hip_bfloat16* __restrict__ vb)
{
    __shared__ __align__(16) char Bs[2][16384];   // x cols [128 hw][k 64] bf16
    const int t = threadIdx.x;
    const int lane = t & 63;
    const int wv = t >> 6;
    const int wm = wv >> 1, wn = wv & 1;
    const int fr = lane & 15, fg = lane >> 4;
    const int hw0 = blockIdx.x * 128;
    const int y   = blockIdx.y;
    const int b   = blockIdx.z;
    const int o0s = (y == 4) ? 0 : (128 + y*128);
    const float* xb = x + (size_t)b*NC*NHW + hw0;
    const int oct = t >> 5, hwg = t & 31;   // staging coords
    const __hip_bfloat16* Wrow = Wbf + (size_t)o0s*NC;

    float4 xrA[8], xrB[8];

#define LOADB(j, XR) do {                                                   \
        const float* gp = xb + (size_t)((j)*64 + oct*8)*NHW + hwg*4;        \
        _Pragma("unroll")                                                   \
        for (int e = 0; e < 8; ++e)                                         \
            XR[e] = *(const float4*)(gp + (size_t)e*NHW);                   \
    } while (0)
#define WRITEB(XR, buf) do {                                                \
        _Pragma("unroll")                                                   \
        for (int d = 0; d < 4; ++d) {                                       \
            int row = hwg*4 + d;                                            \
            bf16x8 wv8;                                                     \
            _Pragma("unroll")                                               \
            for (int e = 0; e < 8; ++e)                                     \
                wv8[e] = f2bf_bits(((const float*)&XR[e])[d]);              \
            int slot = oct ^ (row & 7) ^ ((row >> 3) & 7);                  \
            *(bf16x8*)(Bs[buf] + row*128 + (slot << 4)) = wv8;              \
        }                                                                   \
    } while (0)
#define BSLOT(c, gl) (((gl) ^ ((c) & 7) ^ (((c) >> 3) & 7)) << 4)

    LOADB(0, xrA);
    LOADB(1, xrB);
    WRITEB(xrA, 0);
    __syncthreads();

    f32x4 acc[4][4] = {};

    #pragma unroll
    for (int ks = 0; ks < 8; ++ks) {
        const int cur = ks & 1;
        if (ks < 6) {
            if ((ks & 1) == 0) { LOADB(ks+2, xrA); } else { LOADB(ks+2, xrB); }
        }
        #pragma unroll
        for (int kk = 0; kk < 2; ++kk) {
            const int gl = kk*4 + fg;
            bf16x8 m1[4], n1[4];
            if (y == 4) {
                #pragma unroll
                for (int mf = 0; mf < 4; ++mf) {        // m from B rows (hw)
                    int r = wm*64 + mf*16 + fr;
                    m1[mf] = *(const bf16x8*)(Bs[cur] + r*128 + BSLOT(r, gl));
                }
                #pragma unroll
                for (int nf = 0; nf < 4; ++nf) {        // n from W rows, direct
                    int c = wn*64 + nf*16 + fr;
                    n1[nf] = *(const bf16x8*)(Wrow + (size_t)c*NC + ks*64 + gl*8);
                }
            } else {
                #pragma unroll
                for (int mf = 0; mf < 4; ++mf) {        // m from W rows, direct
                    int r = wm*64 + mf*16 + fr;
                    m1[mf] = *(const bf16x8*)(Wrow + (size_t)r*NC + ks*64 + gl*8);
                }
                #pragma unroll
                for (int nf = 0; nf < 4; ++nf) {        // n from B rows (hw)
                    int c = wn*64 + nf*16 + fr;
                    n1[nf] = *(const bf16x8*)(Bs[cur] + c*128 + BSLOT(c, gl));
                }
            }
            #pragma unroll
            for (int mf = 0; mf < 4; ++mf)
                #pragma unroll
                for (int nf = 0; nf < 4; ++nf)
                    acc[mf][nf] = __builtin_amdgcn_mfma_f32_16x16x32_bf16(
                        m1[mf], n1[nf], acc[mf][nf], 0, 0, 0);
        }
        if (ks < 7) {
            if (ks & 1) { WRITEB(xrA, (ks+1)&1); } else { WRITEB(xrB, (ks+1)&1); }
            __syncthreads();
        }
    }
#undef LOADB
#undef WRITEB
#undef BSLOT

    // C/D layout: col=lane&15 (n-frag), row=(lane>>4)*4+reg (m-frag) — verified
    if (y < 4) {
        #pragma unroll
        for (int mf = 0; mf < 4; ++mf) {
            #pragma unroll
            for (int reg = 0; reg < 4; ++reg) {
                int o = o0s + wm*64 + mf*16 + (lane >> 4)*4 + reg;   // 128..639
                float bias = bias_all[o];
                size_t rowbase = ((size_t)b*NC + (o - 128))*NHW;
                #pragma unroll
                for (int nf = 0; nf < 4; ++nf) {
                    int hw = hw0 + wn*64 + nf*16 + (lane & 15);
                    vb[rowbase + hw] = __float2bfloat16(acc[mf][nf][reg] + bias);
                }
            }
        }
    } else {
        #pragma unroll
        for (int mf = 0; mf < 4; ++mf) {
            #pragma unroll
            for (int reg = 0; reg < 4; ++reg) {
                int hwl = wm*64 + mf*16 + (lane >> 4)*4 + reg;
                size_t rbase = ((size_t)b*NHW + hw0 + hwl)*128;
                #pragma unroll
                for (int nf = 0; nf < 4; ++nf) {
                    int col = wn*64 + nf*16 + (lane & 15);   // 0..127 = q|k
                    qkT2[rbase + col] = __float2bfloat16(acc[mf][nf][reg] + bias_all[col]);
                }
            }
        }
    }
}

// K2: per-channel 64x64 spatial transpose: dst[b][c][w][i] = src[b][c][i][w]
__global__ __launch_bounds__(256) void transpose_hw(
    const __hip_bfloat16* __restrict__ src_, __hip_bfloat16* __restrict__ dst_,
    int nch)
{
    __shared__ __align__(16) short tile[4][64*64];
    const int t = threadIdx.x, wv = t >> 6, lane = t & 63;
    const int c = blockIdx.x*4 + wv, b = blockIdx.y;
    const __hip_bfloat16* src = src_ + ((size_t)(b*nch + c))*NHW;
    __hip_bfloat16* dst = dst_ + ((size_t)(b*nch + c))*NHW;
    short* tl = tile[wv];
    #pragma unroll
    for (int s = 0; s < 8; ++s) {
        int i = s*8 + (lane>>3), w0 = (lane&7)*8;
        bf16x8 vv = *(const bf16x8*)(src + i*64 + w0);
        *(bf16x8*)&tl[i*64 + (((w0>>3) ^ ((i>>3)&7)) << 3)] = vv;
    }
    __syncthreads();
    #pragma unroll
    for (int s = 0; s < 8; ++s) {
        int w = s*8 + (lane>>3), i0 = (lane&7)*8;
        bf16x8 ov;
        #pragma unroll
        for (int d = 0; d < 8; ++d)
            ov[d] = tl[(i0+d)*64 + (((w>>3) ^ (lane&7)) << 3) + (w&7)];
        *(bf16x8*)(dst + w*64 + i0) = ov;
    }
}

// K3a: raw scores via MFMA. Block (s, y, b):
//  y=0: C[h][i] = sum_o q[b,o,h,s]*k[b,o,i,s]   -> rawH[b][s][h][i]
//  y=1: C[w][j] = sum_o q[b,o,s,w]*k[b,o,s,j]   -> rawW[b][s][w][j]
__global__ __launch_bounds__(256) void scores_mfma(
    const __hip_bfloat16* __restrict__ qkT2,
    __hip_bfloat16* __restrict__ rawH, __hip_bfloat16* __restrict__ rawW)
{
    __shared__ __align__(16) char Qs[64*128];   // [r][o 64] bf16
    __shared__ __align__(16) char Ks[64*128];
    const int t = threadIdx.x, lane = t & 63, wv = t >> 6;
    const int wm = wv >> 1, wn = wv & 1;
    const int fr = lane & 15, fg = lane >> 4;
    const int s = blockIdx.x, y = blockIdx.y, b = blockIdx.z;
    const __hip_bfloat16* base = qkT2 + (size_t)b * NHW * 128;
    #pragma unroll
    for (int i = 0; i < 2; ++i) {
        int linear = i*256 + t;
        int r = linear >> 3, g = linear & 7;
        int gk = (g ^ (r & 7)) * 8;
        size_t ro = (y == 0) ? ((size_t)(r*64 + s) * 128)
                             : ((size_t)(s*64 + r) * 128);
        gload16(base + ro + gk,      Qs + linear*16);
        gload16(base + ro + 64 + gk, Ks + linear*16);
    }
    __syncthreads();
    f32x4 acc[2][2] = {};
    #pragma unroll
    for (int kk = 0; kk < 2; ++kk) {
        const int gl = kk*4 + fg;
        bf16x8 qf[2], kf[2];
        #pragma unroll
        for (int mf = 0; mf < 2; ++mf) {
            int r = wm*32 + mf*16 + fr;
            qf[mf] = *(const bf16x8*)(Qs + r*128 + ((gl ^ (r & 7)) << 4));
        }
        #pragma unroll
        for (int nf = 0; nf < 2; ++nf) {
            int c = wn*32 + nf*16 + fr;
            kf[nf] = *(const bf16x8*)(Ks + c*128 + ((gl ^ (c & 7)) << 4));
        }
        #pragma unroll
        for (int mf = 0; mf < 2; ++mf)
            #pragma unroll
            for (int nf = 0; nf < 2; ++nf)
                acc[mf][nf] = __builtin_amdgcn_mfma_f32_16x16x32_bf16(
                    qf[mf], kf[nf], acc[mf][nf], 0, 0, 0);
    }
    __hip_bfloat16* dst = (y == 0) ? rawH : rawW;
    const size_t dbase = ((size_t)(b*64 + s)) * 4096;
    #pragma unroll
    for (int mf = 0; mf < 2; ++mf) {
        #pragma unroll
        for (int reg = 0; reg < 4; ++reg) {
            int row = wm*32 + mf*16 + (lane >> 4)*4 + reg;
            #pragma unroll
            for (int nf = 0; nf < 2; ++nf) {
                int col = wn*32 + nf*16 + (lane & 15);
                dst[dbase + (size_t)row*64 + col] = __float2bfloat16(acc[mf][nf][reg]);
            }
        }
    }
}

// K3b: softmax over 128 concat logits per pixel. Block (hb, b).
__global__ __launch_bounds__(256) void softmax_ab(
    const __hip_bfloat16* __restrict__ rawH, const __hip_bfloat16* __restrict__ rawW,
    __hip_bfloat16* __restrict__ aHb, __hip_bfloat16* __restrict__ aWb)
{
    __shared__ float sH[64][65];   // [w][i]
    __shared__ float sW[64][65];   // [w][j]
    __shared__ float red[8][64];
    const int t = threadIdx.x;
    const int w = t & 63, p = t >> 6;
    const int hb = blockIdx.x, b = blockIdx.y;
    #pragma unroll
    for (int i2 = 0; i2 < 2; ++i2) {
        int linear = i2*256 + t;
        int ww = linear >> 3, g = linear & 7;
        bf16x8 hv = *(const bf16x8*)(rawH + (((size_t)(b*64 + ww))*64 + hb)*64 + g*8);
        bf16x8 wvv = *(const bf16x8*)(rawW + (((size_t)(b*64 + hb))*64 + ww)*64 + g*8);
        #pragma unroll
        for (int e = 0; e < 8; ++e) {
            sH[ww][g*8+e] = bfbits_to_f(hv[e]);
            sW[ww][g*8+e] = bfbits_to_f(wvv[e]);
        }
    }
    __syncthreads();
    if (t < 64) sH[t][hb] = -1e30f;   // diag mask i == hb
    __syncthreads();
    float m = -1e30f;
    #pragma unroll
    for (int z = 0; z < 32; ++z) {
        float val = (p < 2) ? sH[w][p*32+z] : sW[w][(p-2)*32+z];
        m = fmaxf(m, val);
    }
    red[p][w] = m;
    __syncthreads();
    float M = fmaxf(fmaxf(red[0][w], red[1][w]), fmaxf(red[2][w], red[3][w]));
    float ssum = 0.f;
    #pragma unroll
    for (int z = 0; z < 32; ++z) {
        float* slot = (p < 2) ? &sH[w][p*32+z] : &sW[w][(p-2)*32+z];
        float e = __expf(*slot - M);
        ssum += e;
        *slot = e;
    }
    red[4+p][w] = ssum;
    __syncthreads();
    float S = red[4][w] + red[5][w] + red[6][w] + red[7][w];
    float rinv = 1.f / S;
    if (p < 2) {
        size_t base = (((size_t)b*NH + w)*NH + hb)*NO + p*32;
        #pragma unroll
        for (int zz = 0; zz < 4; ++zz) {
            bf16x8 pk;
            #pragma unroll
            for (int d = 0; d < 8; ++d)
                pk[d] = f2bf_bits(sH[w][p*32 + zz*8 + d] * rinv);
            *(bf16x8*)(aHb + base + zz*8) = pk;
        }
    } else {
        size_t base = (((size_t)b*NH + hb)*NH + w)*NO + (p-2)*32;
        #pragma unroll
        for (int zz = 0; zz < 4; ++zz) {
            bf16x8 pk;
            #pragma unroll
            for (int d = 0; d < 8; ++d)
                pk[d] = f2bf_bits(sW[w][(p-2)*32 + zz*8 + d] * rinv);
            *(bf16x8*)(aWb + base + zz*8) = pk;
        }
    }
}

// K4: col pass MFMA. Block (w, chalf, b): C[h][c] = sum_i aH[h][i] * vT[c][i].
__global__ __launch_bounds__(256) void col_mfma(
    const __hip_bfloat16* __restrict__ vT, const __hip_bfloat16* __restrict__ aH,
    __hip_bfloat16* __restrict__ PT)
{
    __shared__ __align__(16) char As[64*128];    // aH[w]: [h][i]
    __shared__ __align__(16) char Bs[256*128];   // vT: [c][i]
    const int t = threadIdx.x, lane = t & 63, wn = t >> 6;
    const int fr = lane & 15, fg = lane >> 4;
    const int w = blockIdx.x, chalf = blockIdx.y, b = blockIdx.z;
    const __hip_bfloat16* Ag = aH + ((size_t)(b*NH + w))*4096;
    const __hip_bfloat16* Bg = vT + ((size_t)(b*NC + chalf*256))*NHW + w*64;
    #pragma unroll
    for (int s = 0; s < 2; ++s) {
        int linear = s*256 + t;
        int r = linear >> 3, g = linear & 7;
        gload16(Ag + r*64 + ((g ^ (r&7)) * 8), As + linear*16);
    }
    #pragma unroll
    for (int s = 0; s < 8; ++s) {
        int linear = s*256 + t;
        int r = linear >> 3, g = linear & 7;
        gload16(Bg + (size_t)r*NHW + ((g ^ (r&7)) * 8), Bs + linear*16);
    }
    __syncthreads();
    f32x4 acc[4][4] = {};
    #pragma unroll
    for (int kk = 0; kk < 2; ++kk) {
        int gl = kk*4 + fg;
        bf16x8 af[4], bfv[4];
        #pragma unroll
        for (int mf = 0; mf < 4; ++mf) {
            int r = mf*16 + fr;
            af[mf] = *(const bf16x8*)(As + r*128 + ((gl ^ (r&7)) << 4));
        }
        #pragma unroll
        for (int nf = 0; nf < 4; ++nf) {
            int c = wn*64 + nf*16 + fr;
            bfv[nf] = *(const bf16x8*)(Bs + c*128 + ((gl ^ (c&7)) << 4));
        }
        #pragma unroll
        for (int mf = 0; mf < 4; ++mf)
            #pragma unroll
            for (int nf = 0; nf < 4; ++nf)
                acc[mf][nf] = __builtin_amdgcn_mfma_f32_16x16x32_bf16(
                    af[mf], bfv[nf], acc[mf][nf], 0, 0, 0);
    }
    const size_t base = ((size_t)(b*NH + w))*64*512 + chalf*256;
    #pragma unroll
    for (int mf = 0; mf < 4; ++mf) {
        #pragma unroll
        for (int reg = 0; reg < 4; ++reg) {
            int hh = mf*16 + (lane >> 4)*4 + reg;
            #pragma unroll
            for (int nf = 0; nf < 4; ++nf) {
                int cc = wn*64 + nf*16 + (lane & 15);
                PT[base + (size_t)hh*512 + cc] = __float2bfloat16(acc[mf][nf][reg]);
            }
        }
    }
}

// K5: row pass MFMA + PT add + residual. Block (h, cq, b):
//   C[c][w] = sum_j v[c][j] * aW[w][j];  out = gamma*(C + PT^T) + x
__global__ __launch_bounds__(256) void row_mfma(
    const __hip_bfloat16* __restrict__ vb, const __hip_bfloat16* __restrict__ aW,
    const __hip_bfloat16* __restrict__ PT, const float* __restrict__ x,
    const float* __restrict__ gamma, float* __restrict__ out)
{
    __shared__ __align__(16) char Ws[64*128];   // aW[h]: [w][j]
    __shared__ __align__(16) char Vs[128*128];  // v: [c][j]
    __shared__ __align__(16) short PTs[64*136]; // [w][c]
    const int t = threadIdx.x, lane = t & 63, wm = t >> 6;
    const int fr = lane & 15, fg = lane >> 4;
    const int h = blockIdx.x, cq = blockIdx.y, b = blockIdx.z;
    const int c0 = cq*128;
    const __hip_bfloat16* Ag = aW + ((size_t)(b*NH + h))*4096;
    const __hip_bfloat16* Vg = vb + ((size_t)(b*NC + c0))*NHW + h*64;
    #pragma unroll
    for (int s = 0; s < 2; ++s) {
        int linear = s*256 + t;
        int r = linear >> 3, g = linear & 7;
        gload16(Ag + r*64 + ((g ^ (r&7)) * 8), Ws + linear*16);
    }
    #pragma unroll
    for (int s = 0; s < 4; ++s) {
        int linear = s*256 + t;
        int r = linear >> 3, g = linear & 7;
        gload16(Vg + (size_t)r*NHW + ((g ^ (r&7)) * 8), Vs + linear*16);
    }
    #pragma unroll
    for (int s = 0; s < 4; ++s) {
        int idx = s*256 + t;
        int ww = idx >> 4, cg = idx & 15;
        bf16x8 pv = *(const bf16x8*)(PT + (((size_t)(b*NH + ww))*64 + h)*512 + c0 + cg*8);
        *(bf16x8*)&PTs[ww*136 + cg*8] = pv;
    }
    __syncthreads();
    f32x4 acc[2][4] = {};
    #pragma unroll
    for (int kk = 0; kk < 2; ++kk) {
        int gl = kk*4 + fg;
        bf16x8 vf[2], wf[4];
        #pragma unroll
        for (int mf = 0; mf < 2; ++mf) {
            int c = wm*32 + mf*16 + fr;
            vf[mf] = *(const bf16x8*)(Vs + c*128 + ((gl ^ (c&7)) << 4));
        }
        #pragma unroll
        for (int nf = 0; nf < 4; ++nf) {
            int ww = nf*16 + fr;
            wf[nf] = *(const bf16x8*)(Ws + ww*128 + ((gl ^ (ww&7)) << 4));
        }
        #pragma unroll
        for (int mf = 0; mf < 2; ++mf)
            #pragma unroll
            for (int nf = 0; nf < 4; ++nf)
                acc[mf][nf] = __builtin_amdgcn_mfma_f32_16x16x32_bf16(
                    vf[mf], wf[nf], acc[mf][nf], 0, 0, 0);
    }
    const float g = gamma[0];
    #pragma unroll
    for (int mf = 0; mf < 2; ++mf) {
        #pragma unroll
        for (int reg = 0; reg < 4; ++reg) {
            int cl = wm*32 + mf*16 + (lane >> 4)*4 + reg;
            size_t rowbase = ((size_t)(b*NC + c0 + cl)*NH + h)*NW;
            #pragma unroll
            for (int nf = 0; nf < 4; ++nf) {
                int ww = nf*16 + (lane & 15);
                float ptv = bfbits_to_f(PTs[ww*136 + cl]);
                out[rowbase + ww] = g*(acc[mf][nf][reg] + ptv) + x[rowbase + ww];
            }
        }
    }
}

extern "C" void kernel_launch(void* const* d_in, const int* in_sizes, int n_in,
                              void* d_out, int out_size, void* d_ws, size_t ws_size,
                              hipStream_t stream) {
    (void)in_sizes; (void)n_in; (void)out_size; (void)ws_size;
    const float* x     = (const float*)d_in[0];
    const float* Wq    = (const float*)d_in[1];
    const float* bq    = (const float*)d_in[2];
    const float* Wk    = (const float*)d_in[3];
    const float* bk    = (const float*)d_in[4];
    const float* Wv    = (const float*)d_in[5];
    const float* bv    = (const float*)d_in[6];
    const float* gamma = (const float*)d_in[7];
    float* out = (float*)d_out;

    char* p = (char*)d_ws;
    __hip_bfloat16* Wbf  = (__hip_bfloat16*)(p);               //    655,360
    float* bias_all      = (float*)(p + 655360);               //      2,560
    __hip_bfloat16* qkT2 = (__hip_bfloat16*)(p + 657920);      //  8,388,608
    __hip_bfloat16* vb   = (__hip_bfloat16*)(p + 9046528);     // 33,554,432
    __hip_bfloat16* vT   = (__hip_bfloat16*)(p + 42600960);    // 33,554,432
    __hip_bfloat16* aHb  = (__hip_bfloat16*)(p + 76155392);    //  4,194,304
    __hip_bfloat16* aWb  = (__hip_bfloat16*)(p + 80349696);    //  4,194,304
    __hip_bfloat16* PT   = (__hip_bfloat16*)(p + 84544000);    // 33,554,432
    __hip_bfloat16* rawH = PT;                                 //  aliases PT
    __hip_bfloat16* rawW = (__hip_bfloat16*)(p + 84544000 + 8388608);
    // total 118,098,432 B

    pack_w<<<dim3(640), 256, 0, stream>>>(Wq, bq, Wk, bk, Wv, bv, Wbf, bias_all);
    qkv_fused<<<dim3(32, 5, NB), 256, 0, stream>>>(x, Wbf, bias_all, qkT2, vb);
    transpose_hw<<<dim3(128, NB), 256, 0, stream>>>(vb, vT, NC);
    scores_mfma<<<dim3(64, 2, NB), 256, 0, stream>>>(qkT2, rawH, rawW);
    softmax_ab<<<dim3(NH, NB), 256, 0, stream>>>(rawH, rawW, aHb, aWb);
    col_mfma<<<dim3(NW, 2, NB), 256, 0, stream>>>(vT, aHb, PT);
    row_mfma<<<dim3(NH, 4, NB), 256, 0, stream>>>(vb, aWb, PT, x, gamma, out);
}

// Round 12
// 114.987 us; speedup vs baseline: 1.1943x; 1.1943x over previous
//
#include <hip/hip_runtime.h>
#include <hip/hip_bf16.h>

#define NB 8
#define NC 512
#define NO 64
#define NH 64
#define NW 64
#define NHW 4096

typedef __attribute__((ext_vector_type(8))) short bf16x8;
typedef __attribute__((ext_vector_type(4))) float f32x4;

__device__ __forceinline__ void gload16(const void* g, void* l) {
    __builtin_amdgcn_global_load_lds(
        (const __attribute__((address_space(1))) void*)g,
        (__attribute__((address_space(3))) void*)l, 16, 0, 0);
}

__device__ __forceinline__ short f2bf_bits(float f) {
    __hip_bfloat16 h = __float2bfloat16(f);
    short s; __builtin_memcpy(&s, &h, 2); return s;
}
__device__ __forceinline__ float bfbits_to_f(short s) {
    unsigned int u = ((unsigned int)(unsigned short)s) << 16;
    float f; __builtin_memcpy(&f, &u, 4); return f;
}

// K0a: pack Wq|Wk|Wv -> Wbf[640][512] bf16, biases -> bias_all[640] f32
__global__ __launch_bounds__(256) void pack_w(
    const float* __restrict__ Wq, const float* __restrict__ bq,
    const float* __restrict__ Wk, const float* __restrict__ bk,
    const float* __restrict__ Wv, const float* __restrict__ bv,
    __hip_bfloat16* __restrict__ Wbf, float* __restrict__ bias_all)
{
    const int row = blockIdx.x;
    const int t = threadIdx.x;
    const float* src; float bias;
    if (row < 64)       { src = Wq + row*NC;        bias = bq[row]; }
    else if (row < 128) { src = Wk + (row-64)*NC;   bias = bk[row-64]; }
    else                { src = Wv + (row-128)*NC;  bias = bv[row-128]; }
    for (int i = t; i < NC; i += 256)
        Wbf[(size_t)row*NC + i] = __float2bfloat16(src[i]);
    if (t == 0) bias_all[row] = bias;
}

// K1: mega QKV projection. Block (hw-tile 128, b), 512 threads (8 waves).
// B (x) read f32 DIRECT from global ONCE, converted in-reg, stored full-K
// resident in LDS (128 KB): Bs[row hw][512 k] bf16, octet ko of row at slot
//   j*8 + (oct ^ (row&7) ^ ((row>>3)&7))   (round-10 verified involution).
// A (W) per K-step via gload_lds (round-10 verified slot gl^(row&7)), dbuf.
// 5 o-tiles x 8 K-steps; ot<4 -> v (normal orient), ot==4 -> q|k swapped.
__global__ __launch_bounds__(512) void qkv_mega2(
    const float* __restrict__ x, const __hip_bfloat16* __restrict__ Wbf,
    const float* __restrict__ bias_all,
    __hip_bfloat16* __restrict__ qkT2, __hip_bfloat16* __restrict__ vb)
{
    __shared__ __align__(16) char Bs[131072];     // [128 hw][512 k] bf16
    __shared__ __align__(16) char As[2][16384];   // [128 o][64 k] bf16, dbuf
    const int t = threadIdx.x;
    const int lane = t & 63;
    const int wv = t >> 6;                 // 8 waves
    const int wm = wv >> 2, wn = wv & 3;   // 2(m) x 4(n)
    const int fr = lane & 15, fg = lane >> 4;
    const int hw0 = blockIdx.x * 128;
    const int b   = blockIdx.y;
    const float* xb = x + (size_t)b*NC*NHW + hw0;
    const int oct = t >> 6, hwp = t & 63;  // B-init coords: 8 k-rows x 2 hw

    typedef __attribute__((ext_vector_type(2))) float f32x2;
    f32x2 xrA[8], xrB[8];

#define LOADB(j, XR) do {                                                   \
        const float* gp = xb + (size_t)((j)*64 + oct*8)*NHW + hwp*2;        \
        _Pragma("unroll")                                                   \
        for (int e = 0; e < 8; ++e)                                         \
            XR[e] = *(const f32x2*)(gp + (size_t)e*NHW);                    \
    } while (0)
#define WRITEB(j, XR) do {                                                  \
        _Pragma("unroll")                                                   \
        for (int d = 0; d < 2; ++d) {                                       \
            int row = hwp*2 + d;                                            \
            bf16x8 wv8;                                                     \
            _Pragma("unroll")                                               \
            for (int e = 0; e < 8; ++e) wv8[e] = f2bf_bits(XR[e][d]);       \
            int slot = (j)*8 + (oct ^ (row & 7) ^ ((row >> 3) & 7));        \
            *(bf16x8*)(Bs + row*1024 + (slot << 4)) = wv8;                  \
        }                                                                   \
    } while (0)
#define BSLOT(c, gl, ks) ((((ks)*8 + ((gl) ^ ((c) & 7) ^ (((c) >> 3) & 7))) << 4))
#define STAGE_A(o0s, ksrc, buf) do {                                        \
        _Pragma("unroll")                                                   \
        for (int s = 0; s < 2; ++s) {                                       \
            int linear = s*512 + t;                                         \
            int row = linear >> 3, g = linear & 7;                          \
            int gk = (g ^ (row & 7)) * 8;                                   \
            gload16(Wbf + (size_t)((o0s) + row)*NC + (ksrc)*64 + gk,        \
                    As[buf] + linear*16);                                   \
        }                                                                   \
    } while (0)

    // prologue: first A slice + full B init (depth-2 reg ping-pong)
    STAGE_A(128, 0, 0);
    LOADB(0, xrA); LOADB(1, xrB);
    WRITEB(0, xrA); LOADB(2, xrA);
    WRITEB(1, xrB); LOADB(3, xrB);
    WRITEB(2, xrA); LOADB(4, xrA);
    WRITEB(3, xrB); LOADB(5, xrB);
    WRITEB(4, xrA); LOADB(6, xrA);
    WRITEB(5, xrB); LOADB(7, xrB);
    WRITEB(6, xrA);
    WRITEB(7, xrB);
    __syncthreads();

    int cur = 0;
    for (int ot = 0; ot < 5; ++ot) {
        const bool qk = (ot == 4);
        const int o0s = qk ? 0 : (128 + ot*128);
        f32x4 acc[4][2] = {};
        for (int ks = 0; ks < 8; ++ks) {
            const int nxt = cur ^ 1;
            if (ks < 7)      STAGE_A(o0s, ks+1, nxt);
            else if (ot < 4) STAGE_A((ot == 3) ? 0 : (128 + (ot+1)*128), 0, nxt);

            #pragma unroll
            for (int kk = 0; kk < 2; ++kk) {
                const int gl = kk*4 + fg;
                bf16x8 m1[4], n1[2];
                if (!qk) {
                    #pragma unroll
                    for (int mf = 0; mf < 4; ++mf) {      // m = o rows from A
                        int r = wm*64 + mf*16 + fr;
                        m1[mf] = *(const bf16x8*)(As[cur] + r*128 + ((gl ^ (r & 7)) << 4));
                    }
                    #pragma unroll
                    for (int nf = 0; nf < 2; ++nf) {      // n = hw rows from B
                        int c = wn*32 + nf*16 + fr;
                        n1[nf] = *(const bf16x8*)(Bs + c*1024 + BSLOT(c, gl, ks));
                    }
                } else {
                    #pragma unroll
                    for (int mf = 0; mf < 4; ++mf) {      // m = hw rows from B
                        int r = wm*64 + mf*16 + fr;
                        m1[mf] = *(const bf16x8*)(Bs + r*1024 + BSLOT(r, gl, ks));
                    }
                    #pragma unroll
                    for (int nf = 0; nf < 2; ++nf) {      // n = o rows from A
                        int c = wn*32 + nf*16 + fr;
                        n1[nf] = *(const bf16x8*)(As[cur] + c*128 + ((gl ^ (c & 7)) << 4));
                    }
                }
                #pragma unroll
                for (int mf = 0; mf < 4; ++mf)
                    #pragma unroll
                    for (int nf = 0; nf < 2; ++nf)
                        acc[mf][nf] = __builtin_amdgcn_mfma_f32_16x16x32_bf16(
                            m1[mf], n1[nf], acc[mf][nf], 0, 0, 0);
            }
            __syncthreads();
            cur ^= 1;
        }

        // epilogue (C/D: col=lane&15 = n-frag, row=(lane>>4)*4+reg = m-frag)
        if (!qk) {
            #pragma unroll
            for (int mf = 0; mf < 4; ++mf) {
                #pragma unroll
                for (int reg = 0; reg < 4; ++reg) {
                    int o = o0s + wm*64 + mf*16 + (lane >> 4)*4 + reg;   // 128..639
                    float bias = bias_all[o];
                    size_t rowbase = ((size_t)b*NC + (o - 128))*NHW;
                    #pragma unroll
                    for (int nf = 0; nf < 2; ++nf) {
                        int hw = hw0 + wn*32 + nf*16 + (lane & 15);
                        vb[rowbase + hw] = __float2bfloat16(acc[mf][nf][reg] + bias);
                    }
                }
            }
        } else {
            #pragma unroll
            for (int mf = 0; mf < 4; ++mf) {
                #pragma unroll
                for (int reg = 0; reg < 4; ++reg) {
                    int hwl = wm*64 + mf*16 + (lane >> 4)*4 + reg;
                    size_t rbase = ((size_t)b*NHW + hw0 + hwl)*128;
                    #pragma unroll
                    for (int nf = 0; nf < 2; ++nf) {
                        int col = wn*32 + nf*16 + (lane & 15);   // 0..127 = q|k
                        qkT2[rbase + col] = __float2bfloat16(acc[mf][nf][reg] + bias_all[col]);
                    }
                }
            }
        }
    }
#undef LOADB
#undef WRITEB
#undef BSLOT
#undef STAGE_A
}

// K2: per-channel 64x64 spatial transpose: dst[b][c][w][i] = src[b][c][i][w]
__global__ __launch_bounds__(256) void transpose_hw(
    const __hip_bfloat16* __restrict__ src_, __hip_bfloat16* __restrict__ dst_,
    int nch)
{
    __shared__ __align__(16) short tile[4][64*64];
    const int t = threadIdx.x, wv = t >> 6, lane = t & 63;
    const int c = blockIdx.x*4 + wv, b = blockIdx.y;
    const __hip_bfloat16* src = src_ + ((size_t)(b*nch + c))*NHW;
    __hip_bfloat16* dst = dst_ + ((size_t)(b*nch + c))*NHW;
    short* tl = tile[wv];
    #pragma unroll
    for (int s = 0; s < 8; ++s) {
        int i = s*8 + (lane>>3), w0 = (lane&7)*8;
        bf16x8 vv = *(const bf16x8*)(src + i*64 + w0);
        *(bf16x8*)&tl[i*64 + (((w0>>3) ^ ((i>>3)&7)) << 3)] = vv;
    }
    __syncthreads();
    #pragma unroll
    for (int s = 0; s < 8; ++s) {
        int w = s*8 + (lane>>3), i0 = (lane&7)*8;
        bf16x8 ov;
        #pragma unroll
        for (int d = 0; d < 8; ++d)
            ov[d] = tl[(i0+d)*64 + (((w>>3) ^ (lane&7)) << 3) + (w&7)];
        *(bf16x8*)(dst + w*64 + i0) = ov;
    }
}

// K3a: raw scores via MFMA. Block (s, y, b):
//  y=0: C[h][i] = sum_o q[b,o,h,s]*k[b,o,i,s]   -> rawH[b][s][h][i]
//  y=1: C[w][j] = sum_o q[b,o,s,w]*k[b,o,s,j]   -> rawW[b][s][w][j]
__global__ __launch_bounds__(256) void scores_mfma(
    const __hip_bfloat16* __restrict__ qkT2,
    __hip_bfloat16* __restrict__ rawH, __hip_bfloat16* __restrict__ rawW)
{
    __shared__ __align__(16) char Qs[64*128];   // [r][o 64] bf16
    __shared__ __align__(16) char Ks[64*128];
    const int t = threadIdx.x, lane = t & 63, wv = t >> 6;
    const int wm = wv >> 1, wn = wv & 1;
    const int fr = lane & 15, fg = lane >> 4;
    const int s = blockIdx.x, y = blockIdx.y, b = blockIdx.z;
    const __hip_bfloat16* base = qkT2 + (size_t)b * NHW * 128;
    #pragma unroll
    for (int i = 0; i < 2; ++i) {
        int linear = i*256 + t;
        int r = linear >> 3, g = linear & 7;
        int gk = (g ^ (r & 7)) * 8;
        size_t ro = (y == 0) ? ((size_t)(r*64 + s) * 128)
                             : ((size_t)(s*64 + r) * 128);
        gload16(base + ro + gk,      Qs + linear*16);
        gload16(base + ro + 64 + gk, Ks + linear*16);
    }
    __syncthreads();
    f32x4 acc[2][2] = {};
    #pragma unroll
    for (int kk = 0; kk < 2; ++kk) {
        const int gl = kk*4 + fg;
        bf16x8 qf[2], kf[2];
        #pragma unroll
        for (int mf = 0; mf < 2; ++mf) {
            int r = wm*32 + mf*16 + fr;
            qf[mf] = *(const bf16x8*)(Qs + r*128 + ((gl ^ (r & 7)) << 4));
        }
        #pragma unroll
        for (int nf = 0; nf < 2; ++nf) {
            int c = wn*32 + nf*16 + fr;
            kf[nf] = *(const bf16x8*)(Ks + c*128 + ((gl ^ (c & 7)) << 4));
        }
        #pragma unroll
        for (int mf = 0; mf < 2; ++mf)
            #pragma unroll
            for (int nf = 0; nf < 2; ++nf)
                acc[mf][nf] = __builtin_amdgcn_mfma_f32_16x16x32_bf16(
                    qf[mf], kf[nf], acc[mf][nf], 0, 0, 0);
    }
    __hip_bfloat16* dst = (y == 0) ? rawH : rawW;
    const size_t dbase = ((size_t)(b*64 + s)) * 4096;
    #pragma unroll
    for (int mf = 0; mf < 2; ++mf) {
        #pragma unroll
        for (int reg = 0; reg < 4; ++reg) {
            int row = wm*32 + mf*16 + (lane >> 4)*4 + reg;
            #pragma unroll
            for (int nf = 0; nf < 2; ++nf) {
                int col = wn*32 + nf*16 + (lane & 15);
                dst[dbase + (size_t)row*64 + col] = __float2bfloat16(acc[mf][nf][reg]);
            }
        }
    }
}

// K3b: softmax over 128 concat logits per pixel. Block (hb, b).
__global__ __launch_bounds__(256) void softmax_ab(
    const __hip_bfloat16* __restrict__ rawH, const __hip_bfloat16* __restrict__ rawW,
    __hip_bfloat16* __restrict__ aHb, __hip_bfloat16* __restrict__ aWb)
{
    __shared__ float sH[64][65];   // [w][i]
    __shared__ float sW[64][65];   // [w][j]
    __shared__ float red[8][64];
    const int t = threadIdx.x;
    const int w = t & 63, p = t >> 6;
    const int hb = blockIdx.x, b = blockIdx.y;
    #pragma unroll
    for (int i2 = 0; i2 < 2; ++i2) {
        int linear = i2*256 + t;
        int ww = linear >> 3, g = linear & 7;
        bf16x8 hv = *(const bf16x8*)(rawH + (((size_t)(b*64 + ww))*64 + hb)*64 + g*8);
        bf16x8 wvv = *(const bf16x8*)(rawW + (((size_t)(b*64 + hb))*64 + ww)*64 + g*8);
        #pragma unroll
        for (int e = 0; e < 8; ++e) {
            sH[ww][g*8+e] = bfbits_to_f(hv[e]);
            sW[ww][g*8+e] = bfbits_to_f(wvv[e]);
        }
    }
    __syncthreads();
    if (t < 64) sH[t][hb] = -1e30f;   // diag mask i == hb
    __syncthreads();
    float m = -1e30f;
    #pragma unroll
    for (int z = 0; z < 32; ++z) {
        float val = (p < 2) ? sH[w][p*32+z] : sW[w][(p-2)*32+z];
        m = fmaxf(m, val);
    }
    red[p][w] = m;
    __syncthreads();
    float M = fmaxf(fmaxf(red[0][w], red[1][w]), fmaxf(red[2][w], red[3][w]));
    float ssum = 0.f;
    #pragma unroll
    for (int z = 0; z < 32; ++z) {
        float* slot = (p < 2) ? &sH[w][p*32+z] : &sW[w][(p-2)*32+z];
        float e = __expf(*slot - M);
        ssum += e;
        *slot = e;
    }
    red[4+p][w] = ssum;
    __syncthreads();
    float S = red[4][w] + red[5][w] + red[6][w] + red[7][w];
    float rinv = 1.f / S;
    if (p < 2) {
        size_t base = (((size_t)b*NH + w)*NH + hb)*NO + p*32;
        #pragma unroll
        for (int zz = 0; zz < 4; ++zz) {
            bf16x8 pk;
            #pragma unroll
            for (int d = 0; d < 8; ++d)
                pk[d] = f2bf_bits(sH[w][p*32 + zz*8 + d] * rinv);
            *(bf16x8*)(aHb + base + zz*8) = pk;
        }
    } else {
        size_t base = (((size_t)b*NH + hb)*NH + w)*NO + (p-2)*32;
        #pragma unroll
        for (int zz = 0; zz < 4; ++zz) {
            bf16x8 pk;
            #pragma unroll
            for (int d = 0; d < 8; ++d)
                pk[d] = f2bf_bits(sW[w][(p-2)*32 + zz*8 + d] * rinv);
            *(bf16x8*)(aWb + base + zz*8) = pk;
        }
    }
}

// K4: col pass MFMA. Block (w, chalf, b): C[h][c] = sum_i aH[h][i] * vT[c][i].
__global__ __launch_bounds__(256) void col_mfma(
    const __hip_bfloat16* __restrict__ vT, const __hip_bfloat16* __restrict__ aH,
    __hip_bfloat16* __restrict__ PT)
{
    __shared__ __align__(16) char As[64*128];    // aH[w]: [h][i]
    __shared__ __align__(16) char Bs[256*128];   // vT: [c][i]
    const int t = threadIdx.x, lane = t & 63, wn = t >> 6;
    const int fr = lane & 15, fg = lane >> 4;
    const int w = blockIdx.x, chalf = blockIdx.y, b = blockIdx.z;
    const __hip_bfloat16* Ag = aH + ((size_t)(b*NH + w))*4096;
    const __hip_bfloat16* Bg = vT + ((size_t)(b*NC + chalf*256))*NHW + w*64;
    #pragma unroll
    for (int s = 0; s < 2; ++s) {
        int linear = s*256 + t;
        int r = linear >> 3, g = linear & 7;
        gload16(Ag + r*64 + ((g ^ (r&7)) * 8), As + linear*16);
    }
    #pragma unroll
    for (int s = 0; s < 8; ++s) {
        int linear = s*256 + t;
        int r = linear >> 3, g = linear & 7;
        gload16(Bg + (size_t)r*NHW + ((g ^ (r&7)) * 8), Bs + linear*16);
    }
    __syncthreads();
    f32x4 acc[4][4] = {};
    #pragma unroll
    for (int kk = 0; kk < 2; ++kk) {
        int gl = kk*4 + fg;
        bf16x8 af[4], bfv[4];
        #pragma unroll
        for (int mf = 0; mf < 4; ++mf) {
            int r = mf*16 + fr;
            af[mf] = *(const bf16x8*)(As + r*128 + ((gl ^ (r&7)) << 4));
        }
        #pragma unroll
        for (int nf = 0; nf < 4; ++nf) {
            int c = wn*64 + nf*16 + fr;
            bfv[nf] = *(const bf16x8*)(Bs + c*128 + ((gl ^ (c&7)) << 4));
        }
        #pragma unroll
        for (int mf = 0; mf < 4; ++mf)
            #pragma unroll
            for (int nf = 0; nf < 4; ++nf)
                acc[mf][nf] = __builtin_amdgcn_mfma_f32_16x16x32_bf16(
                    af[mf], bfv[nf], acc[mf][nf], 0, 0, 0);
    }
    const size_t base = ((size_t)(b*NH + w))*64*512 + chalf*256;
    #pragma unroll
    for (int mf = 0; mf < 4; ++mf) {
        #pragma unroll
        for (int reg = 0; reg < 4; ++reg) {
            int hh = mf*16 + (lane >> 4)*4 + reg;
            #pragma unroll
            for (int nf = 0; nf < 4; ++nf) {
                int cc = wn*64 + nf*16 + (lane & 15);
                PT[base + (size_t)hh*512 + cc] = __float2bfloat16(acc[mf][nf][reg]);
            }
        }
    }
}

// K5: row pass MFMA + PT add + residual. Block (h, cq, b):
//   C[c][w] = sum_j v[c][j] * aW[w][j];  out = gamma*(C + PT^T) + x
__global__ __launch_bounds__(256) void row_mfma(
    const __hip_bfloat16* __restrict__ vb, const __hip_bfloat16* __restrict__ aW,
    const __hip_bfloat16* __restrict__ PT, const float* __restrict__ x,
    const float* __restrict__ gamma, float* __restrict__ out)
{
    __shared__ __align__(16) char Ws[64*128];   // aW[h]: [w][j]
    __shared__ __align__(16) char Vs[128*128];  // v: [c][j]
    __shared__ __align__(16) short PTs[64*136]; // [w][c]
    const int t = threadIdx.x, lane = t & 63, wm = t >> 6;
    const int fr = lane & 15, fg = lane >> 4;
    const int h = blockIdx.x, cq = blockIdx.y, b = blockIdx.z;
    const int c0 = cq*128;
    const __hip_bfloat16* Ag = aW + ((size_t)(b*NH + h))*4096;
    const __hip_bfloat16* Vg = vb + ((size_t)(b*NC + c0))*NHW + h*64;
    #pragma unroll
    for (int s = 0; s < 2; ++s) {
        int linear = s*256 + t;
        int r = linear >> 3, g = linear & 7;
        gload16(Ag + r*64 + ((g ^ (r&7)) * 8), Ws + linear*16);
    }
    #pragma unroll
    for (int s = 0; s < 4; ++s) {
        int linear = s*256 + t;
        int r = linear >> 3, g = linear & 7;
        gload16(Vg + (size_t)r*NHW + ((g ^ (r&7)) * 8), Vs + linear*16);
    }
    #pragma unroll
    for (int s = 0; s < 4; ++s) {
        int idx = s*256 + t;
        int ww = idx >> 4, cg = idx & 15;
        bf16x8 pv = *(const bf16x8*)(PT + (((size_t)(b*NH + ww))*64 + h)*512 + c0 + cg*8);
        *(bf16x8*)&PTs[ww*136 + cg*8] = pv;
    }
    __syncthreads();
    f32x4 acc[2][4] = {};
    #pragma unroll
    for (int kk = 0; kk < 2; ++kk) {
        int gl = kk*4 + fg;
        bf16x8 vf[2], wf[4];
        #pragma unroll
        for (int mf = 0; mf < 2; ++mf) {
            int c = wm*32 + mf*16 + fr;
            vf[mf] = *(const bf16x8*)(Vs + c*128 + ((gl ^ (c&7)) << 4));
        }
        #pragma unroll
        for (int nf = 0; nf < 4; ++nf) {
            int ww = nf*16 + fr;
            wf[nf] = *(const bf16x8*)(Ws + ww*128 + ((gl ^ (ww&7)) << 4));
        }
        #pragma unroll
        for (int mf = 0; mf < 2; ++mf)
            #pragma unroll
            for (int nf = 0; nf < 4; ++nf)
                acc[mf][nf] = __builtin_amdgcn_mfma_f32_16x16x32_bf16(
                    vf[mf], wf[nf], acc[mf][nf], 0, 0, 0);
    }
    const float g = gamma[0];
    #pragma unroll
    for (int mf = 0; mf < 2; ++mf) {
        #pragma unroll
        for (int reg = 0; reg < 4; ++reg) {
            int cl = wm*32 + mf*16 + (lane >> 4)*4 + reg;
            size_t rowbase = ((size_t)(b*NC + c0 + cl)*NH + h)*NW;
            #pragma unroll
            for (int nf = 0; nf < 4; ++nf) {
                int ww = nf*16 + (lane & 15);
                float ptv = bfbits_to_f(PTs[ww*136 + cl]);
                out[rowbase + ww] = g*(acc[mf][nf][reg] + ptv) + x[rowbase + ww];
            }
        }
    }
}

extern "C" void kernel_launch(void* const* d_in, const int* in_sizes, int n_in,
                              void* d_out, int out_size, void* d_ws, size_t ws_size,
                              hipStream_t stream) {
    (void)in_sizes; (void)n_in; (void)out_size; (void)ws_size;
    const float* x     = (const float*)d_in[0];
    const float* Wq    = (const float*)d_in[1];
    const float* bq    = (const float*)d_in[2];
    const float* Wk    = (const float*)d_in[3];
    const float* bk    = (const float*)d_in[4];
    const float* Wv    = (const float*)d_in[5];
    const float* bv    = (const float*)d_in[6];
    const float* gamma = (const float*)d_in[7];
    float* out = (float*)d_out;

    char* p = (char*)d_ws;
    __hip_bfloat16* Wbf  = (__hip_bfloat16*)(p);               //    655,360
    float* bias_all      = (float*)(p + 655360);               //      2,560
    __hip_bfloat16* qkT2 = (__hip_bfloat16*)(p + 657920);      //  8,388,608
    __hip_bfloat16* vb   = (__hip_bfloat16*)(p + 9046528);     // 33,554,432
    __hip_bfloat16* vT   = (__hip_bfloat16*)(p + 42600960);    // 33,554,432
    __hip_bfloat16* aHb  = (__hip_bfloat16*)(p + 76155392);    //  4,194,304
    __hip_bfloat16* aWb  = (__hip_bfloat16*)(p + 80349696);    //  4,194,304
    __hip_bfloat16* PT   = (__hip_bfloat16*)(p + 84544000);    // 33,554,432
    __hip_bfloat16* rawH = PT;                                 //  aliases PT
    __hip_bfloat16* rawW = (__hip_bfloat16*)(p + 84544000 + 8388608);
    // total 118,098,432 B

    pack_w<<<dim3(640), 256, 0, stream>>>(Wq, bq, Wk, bk, Wv, bv, Wbf, bias_all);
    qkv_mega2<<<dim3(32, NB), 512, 0, stream>>>(x, Wbf, bias_all, qkT2, vb);
    transpose_hw<<<dim3(128, NB), 256, 0, stream>>>(vb, vT, NC);
    scores_mfma<<<dim3(64, 2, NB), 256, 0, stream>>>(qkT2, rawH, rawW);
    softmax_ab<<<dim3(NH, NB), 256, 0, stream>>>(rawH, rawW, aHb, aWb);
    col_mfma<<<dim3(NW, 2, NB), 256, 0, stream>>>(vT, aHb, PT);
    row_mfma<<<dim3(NH, 4, NB), 256, 0, stream>>>(vb, aWb, PT, x, gamma, out);
}

// Round 13
// 112.926 us; speedup vs baseline: 1.2161x; 1.0183x over previous
//
#include <hip/hip_runtime.h>
#include <hip/hip_bf16.h>

#define NB 8
#define NC 512
#define NO 64
#define NH 64
#define NW 64
#define NHW 4096

typedef __attribute__((ext_vector_type(8))) short bf16x8;
typedef __attribute__((ext_vector_type(4))) float f32x4;

__device__ __forceinline__ void gload16(const void* g, void* l) {
    __builtin_amdgcn_global_load_lds(
        (const __attribute__((address_space(1))) void*)g,
        (__attribute__((address_space(3))) void*)l, 16, 0, 0);
}

__device__ __forceinline__ short f2bf_bits(float f) {
    __hip_bfloat16 h = __float2bfloat16(f);
    short s; __builtin_memcpy(&s, &h, 2); return s;
}
__device__ __forceinline__ float bfbits_to_f(short s) {
    unsigned int u = ((unsigned int)(unsigned short)s) << 16;
    float f; __builtin_memcpy(&f, &u, 4); return f;
}

// K0a: pack Wq|Wk|Wv -> Wbf[640][512] bf16, biases -> bias_all[640] f32
__global__ __launch_bounds__(256) void pack_w(
    const float* __restrict__ Wq, const float* __restrict__ bq,
    const float* __restrict__ Wk, const float* __restrict__ bk,
    const float* __restrict__ Wv, const float* __restrict__ bv,
    __hip_bfloat16* __restrict__ Wbf, float* __restrict__ bias_all)
{
    const int row = blockIdx.x;
    const int t = threadIdx.x;
    const float* src; float bias;
    if (row < 64)       { src = Wq + row*NC;        bias = bq[row]; }
    else if (row < 128) { src = Wk + (row-64)*NC;   bias = bk[row-64]; }
    else                { src = Wv + (row-128)*NC;  bias = bv[row-128]; }
    for (int i = t; i < NC; i += 256)
        Wbf[(size_t)row*NC + i] = __float2bfloat16(src[i]);
    if (t == 0) bias_all[row] = bias;
}

// K1: mega QKV projection. Block (hw-tile 128, b), 512 threads (8 waves).
// B (x) read f32 DIRECT from global ONCE, converted in-reg, stored full-K
// resident in LDS (128 KB). A (W) per K-step via gload_lds, double-buffered.
// 5 o-tiles x 8 K-steps; ot<4 -> v (normal orient), ot==4 -> q|k swapped.
__global__ __launch_bounds__(512) void qkv_mega2(
    const float* __restrict__ x, const __hip_bfloat16* __restrict__ Wbf,
    const float* __restrict__ bias_all,
    __hip_bfloat16* __restrict__ qkT2, __hip_bfloat16* __restrict__ vb)
{
    __shared__ __align__(16) char Bs[131072];     // [128 hw][512 k] bf16
    __shared__ __align__(16) char As[2][16384];   // [128 o][64 k] bf16, dbuf
    const int t = threadIdx.x;
    const int lane = t & 63;
    const int wv = t >> 6;                 // 8 waves
    const int wm = wv >> 2, wn = wv & 3;   // 2(m) x 4(n)
    const int fr = lane & 15, fg = lane >> 4;
    const int hw0 = blockIdx.x * 128;
    const int b   = blockIdx.y;
    const float* xb = x + (size_t)b*NC*NHW + hw0;
    const int oct = t >> 6, hwp = t & 63;  // B-init coords: 8 k-rows x 2 hw

    typedef __attribute__((ext_vector_type(2))) float f32x2;
    f32x2 xrA[8], xrB[8];

#define LOADB(j, XR) do {                                                   \
        const float* gp = xb + (size_t)((j)*64 + oct*8)*NHW + hwp*2;        \
        _Pragma("unroll")                                                   \
        for (int e = 0; e < 8; ++e)                                         \
            XR[e] = *(const f32x2*)(gp + (size_t)e*NHW);                    \
    } while (0)
#define WRITEB(j, XR) do {                                                  \
        _Pragma("unroll")                                                   \
        for (int d = 0; d < 2; ++d) {                                       \
            int row = hwp*2 + d;                                            \
            bf16x8 wv8;                                                     \
            _Pragma("unroll")                                               \
            for (int e = 0; e < 8; ++e) wv8[e] = f2bf_bits(XR[e][d]);       \
            int slot = (j)*8 + (oct ^ (row & 7) ^ ((row >> 3) & 7));        \
            *(bf16x8*)(Bs + row*1024 + (slot << 4)) = wv8;                  \
        }                                                                   \
    } while (0)
#define BSLOT(c, gl, ks) ((((ks)*8 + ((gl) ^ ((c) & 7) ^ (((c) >> 3) & 7))) << 4))
#define STAGE_A(o0s, ksrc, buf) do {                                        \
        _Pragma("unroll")                                                   \
        for (int s = 0; s < 2; ++s) {                                       \
            int linear = s*512 + t;                                         \
            int row = linear >> 3, g = linear & 7;                          \
            int gk = (g ^ (row & 7)) * 8;                                   \
            gload16(Wbf + (size_t)((o0s) + row)*NC + (ksrc)*64 + gk,        \
                    As[buf] + linear*16);                                   \
        }                                                                   \
    } while (0)

    // prologue: first A slice + full B init (depth-2 reg ping-pong)
    STAGE_A(128, 0, 0);
    LOADB(0, xrA); LOADB(1, xrB);
    WRITEB(0, xrA); LOADB(2, xrA);
    WRITEB(1, xrB); LOADB(3, xrB);
    WRITEB(2, xrA); LOADB(4, xrA);
    WRITEB(3, xrB); LOADB(5, xrB);
    WRITEB(4, xrA); LOADB(6, xrA);
    WRITEB(5, xrB); LOADB(7, xrB);
    WRITEB(6, xrA);
    WRITEB(7, xrB);
    __syncthreads();

    int cur = 0;
    for (int ot = 0; ot < 5; ++ot) {
        const bool qk = (ot == 4);
        const int o0s = qk ? 0 : (128 + ot*128);
        f32x4 acc[4][2] = {};
        for (int ks = 0; ks < 8; ++ks) {
            const int nxt = cur ^ 1;
            if (ks < 7)      STAGE_A(o0s, ks+1, nxt);
            else if (ot < 4) STAGE_A((ot == 3) ? 0 : (128 + (ot+1)*128), 0, nxt);

            #pragma unroll
            for (int kk = 0; kk < 2; ++kk) {
                const int gl = kk*4 + fg;
                bf16x8 m1[4], n1[2];
                if (!qk) {
                    #pragma unroll
                    for (int mf = 0; mf < 4; ++mf) {      // m = o rows from A
                        int r = wm*64 + mf*16 + fr;
                        m1[mf] = *(const bf16x8*)(As[cur] + r*128 + ((gl ^ (r & 7)) << 4));
                    }
                    #pragma unroll
                    for (int nf = 0; nf < 2; ++nf) {      // n = hw rows from B
                        int c = wn*32 + nf*16 + fr;
                        n1[nf] = *(const bf16x8*)(Bs + c*1024 + BSLOT(c, gl, ks));
                    }
                } else {
                    #pragma unroll
                    for (int mf = 0; mf < 4; ++mf) {      // m = hw rows from B
                        int r = wm*64 + mf*16 + fr;
                        m1[mf] = *(const bf16x8*)(Bs + r*1024 + BSLOT(r, gl, ks));
                    }
                    #pragma unroll
                    for (int nf = 0; nf < 2; ++nf) {      // n = o rows from A
                        int c = wn*32 + nf*16 + fr;
                        n1[nf] = *(const bf16x8*)(As[cur] + c*128 + ((gl ^ (c & 7)) << 4));
                    }
                }
                #pragma unroll
                for (int mf = 0; mf < 4; ++mf)
                    #pragma unroll
                    for (int nf = 0; nf < 2; ++nf)
                        acc[mf][nf] = __builtin_amdgcn_mfma_f32_16x16x32_bf16(
                            m1[mf], n1[nf], acc[mf][nf], 0, 0, 0);
            }
            __syncthreads();
            cur ^= 1;
        }

        // epilogue (C/D: col=lane&15 = n-frag, row=(lane>>4)*4+reg = m-frag)
        if (!qk) {
            #pragma unroll
            for (int mf = 0; mf < 4; ++mf) {
                #pragma unroll
                for (int reg = 0; reg < 4; ++reg) {
                    int o = o0s + wm*64 + mf*16 + (lane >> 4)*4 + reg;   // 128..639
                    float bias = bias_all[o];
                    size_t rowbase = ((size_t)b*NC + (o - 128))*NHW;
                    #pragma unroll
                    for (int nf = 0; nf < 2; ++nf) {
                        int hw = hw0 + wn*32 + nf*16 + (lane & 15);
                        vb[rowbase + hw] = __float2bfloat16(acc[mf][nf][reg] + bias);
                    }
                }
            }
        } else {
            #pragma unroll
            for (int mf = 0; mf < 4; ++mf) {
                #pragma unroll
                for (int reg = 0; reg < 4; ++reg) {
                    int hwl = wm*64 + mf*16 + (lane >> 4)*4 + reg;
                    size_t rbase = ((size_t)b*NHW + hw0 + hwl)*128;
                    #pragma unroll
                    for (int nf = 0; nf < 2; ++nf) {
                        int col = wn*32 + nf*16 + (lane & 15);   // 0..127 = q|k
                        qkT2[rbase + col] = __float2bfloat16(acc[mf][nf][reg] + bias_all[col]);
                    }
                }
            }
        }
    }
#undef LOADB
#undef WRITEB
#undef BSLOT
#undef STAGE_A
}

// K3a: raw scores via MFMA. Block (s, y, b):
//  y=0: C[h][i] = sum_o q[b,o,h,s]*k[b,o,i,s]   -> rawH[b][s][h][i]
//  y=1: C[w][j] = sum_o q[b,o,s,w]*k[b,o,s,j]   -> rawW[b][s][w][j]
__global__ __launch_bounds__(256) void scores_mfma(
    const __hip_bfloat16* __restrict__ qkT2,
    __hip_bfloat16* __restrict__ rawH, __hip_bfloat16* __restrict__ rawW)
{
    __shared__ __align__(16) char Qs[64*128];   // [r][o 64] bf16
    __shared__ __align__(16) char Ks[64*128];
    const int t = threadIdx.x, lane = t & 63, wv = t >> 6;
    const int wm = wv >> 1, wn = wv & 1;
    const int fr = lane & 15, fg = lane >> 4;
    const int s = blockIdx.x, y = blockIdx.y, b = blockIdx.z;
    const __hip_bfloat16* base = qkT2 + (size_t)b * NHW * 128;
    #pragma unroll
    for (int i = 0; i < 2; ++i) {
        int linear = i*256 + t;
        int r = linear >> 3, g = linear & 7;
        int gk = (g ^ (r & 7)) * 8;
        size_t ro = (y == 0) ? ((size_t)(r*64 + s) * 128)
                             : ((size_t)(s*64 + r) * 128);
        gload16(base + ro + gk,      Qs + linear*16);
        gload16(base + ro + 64 + gk, Ks + linear*16);
    }
    __syncthreads();
    f32x4 acc[2][2] = {};
    #pragma unroll
    for (int kk = 0; kk < 2; ++kk) {
        const int gl = kk*4 + fg;
        bf16x8 qf[2], kf[2];
        #pragma unroll
        for (int mf = 0; mf < 2; ++mf) {
            int r = wm*32 + mf*16 + fr;
            qf[mf] = *(const bf16x8*)(Qs + r*128 + ((gl ^ (r & 7)) << 4));
        }
        #pragma unroll
        for (int nf = 0; nf < 2; ++nf) {
            int c = wn*32 + nf*16 + fr;
            kf[nf] = *(const bf16x8*)(Ks + c*128 + ((gl ^ (c & 7)) << 4));
        }
        #pragma unroll
        for (int mf = 0; mf < 2; ++mf)
            #pragma unroll
            for (int nf = 0; nf < 2; ++nf)
                acc[mf][nf] = __builtin_amdgcn_mfma_f32_16x16x32_bf16(
                    qf[mf], kf[nf], acc[mf][nf], 0, 0, 0);
    }
    __hip_bfloat16* dst = (y == 0) ? rawH : rawW;
    const size_t dbase = ((size_t)(b*64 + s)) * 4096;
    #pragma unroll
    for (int mf = 0; mf < 2; ++mf) {
        #pragma unroll
        for (int reg = 0; reg < 4; ++reg) {
            int row = wm*32 + mf*16 + (lane >> 4)*4 + reg;
            #pragma unroll
            for (int nf = 0; nf < 2; ++nf) {
                int col = wn*32 + nf*16 + (lane & 15);
                dst[dbase + (size_t)row*64 + col] = __float2bfloat16(acc[mf][nf][reg]);
            }
        }
    }
}

// K3b+K2 fused: blocks 0..1023 transpose v (dst[b][c][w][i]=src[b][c][i][w]);
// blocks 1024..1535 softmax over 128 concat logits per pixel (block (hb,b)).
// Independent work co-scheduled; one shared smem arena (max of both needs).
__global__ __launch_bounds__(256) void sm_tv(
    const __hip_bfloat16* __restrict__ vb, __hip_bfloat16* __restrict__ vT,
    const __hip_bfloat16* __restrict__ rawH, const __hip_bfloat16* __restrict__ rawW,
    __hip_bfloat16* __restrict__ aHb, __hip_bfloat16* __restrict__ aWb)
{
    __shared__ __align__(16) char smem[35328];
    const int bid = blockIdx.x;
    const int t = threadIdx.x;
    if (bid < 1024) {
        // ---- transpose_hw for v (nch=512), orig grid (128, 8) ----
        const int bx = bid & 127, b = bid >> 7;
        const int wv = t >> 6, lane = t & 63;
        const int c = bx*4 + wv;
        const __hip_bfloat16* src = vb + ((size_t)(b*NC + c))*NHW;
        __hip_bfloat16* dst = vT + ((size_t)(b*NC + c))*NHW;
        short* tl = (short*)smem + wv*4096;
        #pragma unroll
        for (int s = 0; s < 8; ++s) {
            int i = s*8 + (lane>>3), w0 = (lane&7)*8;
            bf16x8 vv = *(const bf16x8*)(src + i*64 + w0);
            *(bf16x8*)&tl[i*64 + (((w0>>3) ^ ((i>>3)&7)) << 3)] = vv;
        }
        __syncthreads();
        #pragma unroll
        for (int s = 0; s < 8; ++s) {
            int w = s*8 + (lane>>3), i0 = (lane&7)*8;
            bf16x8 ov;
            #pragma unroll
            for (int d = 0; d < 8; ++d)
                ov[d] = tl[(i0+d)*64 + (((w>>3) ^ (lane&7)) << 3) + (w&7)];
            *(bf16x8*)(dst + w*64 + i0) = ov;
        }
    } else {
        // ---- softmax_ab, orig block (hb, b) ----
        const int r = bid - 1024;
        const int hb = r & 63, b = r >> 6;
        float* sH  = (float*)smem;          // [64][65]
        float* sW  = sH + 64*65;            // [64][65]
        float* red = sW + 64*65;            // [8][64]
        const int w = t & 63, p = t >> 6;
        #pragma unroll
        for (int i2 = 0; i2 < 2; ++i2) {
            int linear = i2*256 + t;
            int ww = linear >> 3, g = linear & 7;
            bf16x8 hv  = *(const bf16x8*)(rawH + (((size_t)(b*64 + ww))*64 + hb)*64 + g*8);
            bf16x8 wvv = *(const bf16x8*)(rawW + (((size_t)(b*64 + hb))*64 + ww)*64 + g*8);
            #pragma unroll
            for (int e = 0; e < 8; ++e) {
                sH[ww*65 + g*8+e] = bfbits_to_f(hv[e]);
                sW[ww*65 + g*8+e] = bfbits_to_f(wvv[e]);
            }
        }
        __syncthreads();
        if (t < 64) sH[t*65 + hb] = -1e30f;   // diag mask i == hb
        __syncthreads();
        float m = -1e30f;
        #pragma unroll
        for (int z = 0; z < 32; ++z) {
            float val = (p < 2) ? sH[w*65 + p*32+z] : sW[w*65 + (p-2)*32+z];
            m = fmaxf(m, val);
        }
        red[p*64 + w] = m;
        __syncthreads();
        float M = fmaxf(fmaxf(red[0*64+w], red[1*64+w]), fmaxf(red[2*64+w], red[3*64+w]));
        float ssum = 0.f;
        #pragma unroll
        for (int z = 0; z < 32; ++z) {
            float* slot = (p < 2) ? &sH[w*65 + p*32+z] : &sW[w*65 + (p-2)*32+z];
            float e = __expf(*slot - M);
            ssum += e;
            *slot = e;
        }
        red[(4+p)*64 + w] = ssum;
        __syncthreads();
        float S = red[4*64+w] + red[5*64+w] + red[6*64+w] + red[7*64+w];
        float rinv = 1.f / S;
        if (p < 2) {
            size_t base = (((size_t)b*NH + w)*NH + hb)*NO + p*32;
            #pragma unroll
            for (int zz = 0; zz < 4; ++zz) {
                bf16x8 pk;
                #pragma unroll
                for (int d = 0; d < 8; ++d)
                    pk[d] = f2bf_bits(sH[w*65 + p*32 + zz*8 + d] * rinv);
                *(bf16x8*)(aHb + base + zz*8) = pk;
            }
        } else {
            size_t base = (((size_t)b*NH + hb)*NH + w)*NO + (p-2)*32;
            #pragma unroll
            for (int zz = 0; zz < 4; ++zz) {
                bf16x8 pk;
                #pragma unroll
                for (int d = 0; d < 8; ++d)
                    pk[d] = f2bf_bits(sW[w*65 + (p-2)*32 + zz*8 + d] * rinv);
                *(bf16x8*)(aWb + base + zz*8) = pk;
            }
        }
    }
}

// K4: col pass MFMA. Block (w, chalf, b): C[h][c] = sum_i aH[h][i] * vT[c][i].
__global__ __launch_bounds__(256) void col_mfma(
    const __hip_bfloat16* __restrict__ vT, const __hip_bfloat16* __restrict__ aH,
    __hip_bfloat16* __restrict__ PT)
{
    __shared__ __align__(16) char As[64*128];    // aH[w]: [h][i]
    __shared__ __align__(16) char Bs[256*128];   // vT: [c][i]
    const int t = threadIdx.x, lane = t & 63, wn = t >> 6;
    const int fr = lane & 15, fg = lane >> 4;
    const int w = blockIdx.x, chalf = blockIdx.y, b = blockIdx.z;
    const __hip_bfloat16* Ag = aH + ((size_t)(b*NH + w))*4096;
    const __hip_bfloat16* Bg = vT + ((size_t)(b*NC + chalf*256))*NHW + w*64;
    #pragma unroll
    for (int s = 0; s < 2; ++s) {
        int linear = s*256 + t;
        int r = linear >> 3, g = linear & 7;
        gload16(Ag + r*64 + ((g ^ (r&7)) * 8), As + linear*16);
    }
    #pragma unroll
    for (int s = 0; s < 8; ++s) {
        int linear = s*256 + t;
        int r = linear >> 3, g = linear & 7;
        gload16(Bg + (size_t)r*NHW + ((g ^ (r&7)) * 8), Bs + linear*16);
    }
    __syncthreads();
    f32x4 acc[4][4] = {};
    #pragma unroll
    for (int kk = 0; kk < 2; ++kk) {
        int gl = kk*4 + fg;
        bf16x8 af[4], bfv[4];
        #pragma unroll
        for (int mf = 0; mf < 4; ++mf) {
            int r = mf*16 + fr;
            af[mf] = *(const bf16x8*)(As + r*128 + ((gl ^ (r&7)) << 4));
        }
        #pragma unroll
        for (int nf = 0; nf < 4; ++nf) {
            int c = wn*64 + nf*16 + fr;
            bfv[nf] = *(const bf16x8*)(Bs + c*128 + ((gl ^ (c&7)) << 4));
        }
        #pragma unroll
        for (int mf = 0; mf < 4; ++mf)
            #pragma unroll
            for (int nf = 0; nf < 4; ++nf)
                acc[mf][nf] = __builtin_amdgcn_mfma_f32_16x16x32_bf16(
                    af[mf], bfv[nf], acc[mf][nf], 0, 0, 0);
    }
    const size_t base = ((size_t)(b*NH + w))*64*512 + chalf*256;
    #pragma unroll
    for (int mf = 0; mf < 4; ++mf) {
        #pragma unroll
        for (int reg = 0; reg < 4; ++reg) {
            int hh = mf*16 + (lane >> 4)*4 + reg;
            #pragma unroll
            for (int nf = 0; nf < 4; ++nf) {
                int cc = wn*64 + nf*16 + (lane & 15);
                PT[base + (size_t)hh*512 + cc] = __float2bfloat16(acc[mf][nf][reg]);
            }
        }
    }
}

// K5: row pass MFMA + PT add + residual. Block (h, cq, b):
//   C[c][w] = sum_j v[c][j] * aW[w][j];  out = gamma*(C + PT^T) + x
__global__ __launch_bounds__(256) void row_mfma(
    const __hip_bfloat16* __restrict__ vb, const __hip_bfloat16* __restrict__ aW,
    const __hip_bfloat16* __restrict__ PT, const float* __restrict__ x,
    const float* __restrict__ gamma, float* __restrict__ out)
{
    __shared__ __align__(16) char Ws[64*128];   // aW[h]: [w][j]
    __shared__ __align__(16) char Vs[128*128];  // v: [c][j]
    __shared__ __align__(16) short PTs[64*136]; // [w][c]
    const int t = threadIdx.x, lane = t & 63, wm = t >> 6;
    const int fr = lane & 15, fg = lane >> 4;
    const int h = blockIdx.x, cq = blockIdx.y, b = blockIdx.z;
    const int c0 = cq*128;
    const __hip_bfloat16* Ag = aW + ((size_t)(b*NH + h))*4096;
    const __hip_bfloat16* Vg = vb + ((size_t)(b*NC + c0))*NHW + h*64;
    #pragma unroll
    for (int s = 0; s < 2; ++s) {
        int linear = s*256 + t;
        int r = linear >> 3, g = linear & 7;
        gload16(Ag + r*64 + ((g ^ (r&7)) * 8), Ws + linear*16);
    }
    #pragma unroll
    for (int s = 0; s < 4; ++s) {
        int linear = s*256 + t;
        int r = linear >> 3, g = linear & 7;
        gload16(Vg + (size_t)r*NHW + ((g ^ (r&7)) * 8), Vs + linear*16);
    }
    #pragma unroll
    for (int s = 0; s < 4; ++s) {
        int idx = s*256 + t;
        int ww = idx >> 4, cg = idx & 15;
        bf16x8 pv = *(const bf16x8*)(PT + (((size_t)(b*NH + ww))*64 + h)*512 + c0 + cg*8);
        *(bf16x8*)&PTs[ww*136 + cg*8] = pv;
    }
    __syncthreads();
    f32x4 acc[2][4] = {};
    #pragma unroll
    for (int kk = 0; kk < 2; ++kk) {
        int gl = kk*4 + fg;
        bf16x8 vf[2], wf[4];
        #pragma unroll
        for (int mf = 0; mf < 2; ++mf) {
            int c = wm*32 + mf*16 + fr;
            vf[mf] = *(const bf16x8*)(Vs + c*128 + ((gl ^ (c&7)) << 4));
        }
        #pragma unroll
        for (int nf = 0; nf < 4; ++nf) {
            int ww = nf*16 + fr;
            wf[nf] = *(const bf16x8*)(Ws + ww*128 + ((gl ^ (ww&7)) << 4));
        }
        #pragma unroll
        for (int mf = 0; mf < 2; ++mf)
            #pragma unroll
            for (int nf = 0; nf < 4; ++nf)
                acc[mf][nf] = __builtin_amdgcn_mfma_f32_16x16x32_bf16(
                    vf[mf], wf[nf], acc[mf][nf], 0, 0, 0);
    }
    const float g = gamma[0];
    #pragma unroll
    for (int mf = 0; mf < 2; ++mf) {
        #pragma unroll
        for (int reg = 0; reg < 4; ++reg) {
            int cl = wm*32 + mf*16 + (lane >> 4)*4 + reg;
            size_t rowbase = ((size_t)(b*NC + c0 + cl)*NH + h)*NW;
            #pragma unroll
            for (int nf = 0; nf < 4; ++nf) {
                int ww = nf*16 + (lane & 15);
                float ptv = bfbits_to_f(PTs[ww*136 + cl]);
                out[rowbase + ww] = g*(acc[mf][nf][reg] + ptv) + x[rowbase + ww];
            }
        }
    }
}

extern "C" void kernel_launch(void* const* d_in, const int* in_sizes, int n_in,
                              void* d_out, int out_size, void* d_ws, size_t ws_size,
                              hipStream_t stream) {
    (void)in_sizes; (void)n_in; (void)out_size; (void)ws_size;
    const float* x     = (const float*)d_in[0];
    const float* Wq    = (const float*)d_in[1];
    const float* bq    = (const float*)d_in[2];
    const float* Wk    = (const float*)d_in[3];
    const float* bk    = (const float*)d_in[4];
    const float* Wv    = (const float*)d_in[5];
    const float* bv    = (const float*)d_in[6];
    const float* gamma = (const float*)d_in[7];
    float* out = (float*)d_out;

    char* p = (char*)d_ws;
    __hip_bfloat16* Wbf  = (__hip_bfloat16*)(p);               //    655,360
    float* bias_all      = (float*)(p + 655360);               //      2,560
    __hip_bfloat16* qkT2 = (__hip_bfloat16*)(p + 657920);      //  8,388,608
    __hip_bfloat16* vb   = (__hip_bfloat16*)(p + 9046528);     // 33,554,432
    __hip_bfloat16* vT   = (__hip_bfloat16*)(p + 42600960);    // 33,554,432
    __hip_bfloat16* aHb  = (__hip_bfloat16*)(p + 76155392);    //  4,194,304
    __hip_bfloat16* aWb  = (__hip_bfloat16*)(p + 80349696);    //  4,194,304
    __hip_bfloat16* PT   = (__hip_bfloat16*)(p + 84544000);    // 33,554,432
    __hip_bfloat16* rawH = PT;                                 //  aliases PT
    __hip_bfloat16* rawW = (__hip_bfloat16*)(p + 84544000 + 8388608);
    // total 118,098,432 B

    pack_w<<<dim3(640), 256, 0, stream>>>(Wq, bq, Wk, bk, Wv, bv, Wbf, bias_all);
    qkv_mega2<<<dim3(32, NB), 512, 0, stream>>>(x, Wbf, bias_all, qkT2, vb);
    scores_mfma<<<dim3(64, 2, NB), 256, 0, stream>>>(qkT2, rawH, rawW);
    sm_tv<<<dim3(1536), 256, 0, stream>>>(vb, vT, rawH, rawW, aHb, aWb);
    col_mfma<<<dim3(NW, 2, NB), 256, 0, stream>>>(vT, aHb, PT);
    row_mfma<<<dim3(NH, 4, NB), 256, 0, stream>>>(vb, aWb, PT, x, gamma, out);
}